// Round 12
// baseline (283.619 us; speedup 1.0000x reference)
//
#include <hip/hip_runtime.h>
#include <hip/hip_bf16.h>

#define TT 1024
#define AA 16
#define DTS 0.4f
#define EPSV 1e-6f

typedef float f4 __attribute__((ext_vector_type(4)));

// dd components (x,y) of (ado-ado_wo)'' for flat row `row` at time t; 0 at ends
__device__ __forceinline__ float2 dd2(const float2* __restrict__ A,
                                      const float2* __restrict__ B,
                                      int row, int t) {
    if (t <= 0 || t >= TT - 1) return make_float2(0.f, 0.f);
    const float2* a = A + row * TT + t;
    const float2* b = B + row * TT + t;
    float2 am = a[-1], a0 = a[0], ap = a[1];
    float2 bm = b[-1], b0 = b[0], bp = b[1];
    const float s = 1.0f / (DTS * DTS);
    float2 r;
    r.x = ((am.x - bm.x) - 2.f * (a0.x - b0.x) + (ap.x - bp.x)) * s;
    r.y = ((am.y - bm.y) - 2.f * (a0.y - b0.y) + (ap.y - bp.y)) * s;
    return r;
}

// One fused kernel, 2048 blocks x 256 thr, 8 blocks/CU -> ALL blocks resident
// (spin-wait cannot deadlock). Blocks 0..255: compute ws/coef (R4-proven
// coalesced scheme) + zero their out slice, then RELEASE flag. All blocks:
// prefetch pg, ACQUIRE flag (1 polling thread + s_sleep), then R9-proven
// quarter-grad with atomicAdd to out.
__global__ __launch_bounds__(256, 8) void fused_kernel(const float* __restrict__ ado,
                                                       const float* __restrict__ ado_wo,
                                                       const float* __restrict__ pg,
                                                       float* __restrict__ ws,
                                                       float* __restrict__ coef,
                                                       unsigned int* __restrict__ flag,
                                                       float* __restrict__ out) {
    const int g = blockIdx.x;
    const int tid = threadIdx.x;

    // ---------------- grad indices (R9 partition) ----------------
    const int b = g >> 2;          // pair 0..511
    const int qi = g & 3;          // quarter
    const int k1 = b + 1;          // 1..512
    const int k2 = TT - 1 - b;     // 1023..512
    const bool dup = (k1 == k2);   // b == 511
    const int base1 = (k1 - 1) * 8;
    const int base2 = (k2 - 1) * 8;
    const int n1 = (TT - 1) * 8 - base1;   // n1 + n2 = 8192, n1 >= 4096

    const f4* __restrict__ pg4 = (const f4*)pg;
    const f4* __restrict__ coef4 = (const f4*)coef;
    const f4* __restrict__ ws4 = (const f4*)ws;

    // ---------------- prefetch first 4 f4 of my quarter (flag-independent) ---
    f4 pf[4];
    bool pv[4];
    #pragma unroll
    for (int i = 0; i < 4; ++i) {
        int e = qi * 2048 + tid + 256 * i;
        bool s1 = (e < n1);
        pv[i] = s1 || !dup;
        int q = s1 ? (base1 + e) : (base2 + (e - n1));
        int row = s1 ? k1 : k2;
        if (pv[i]) pf[i] = pg4[(size_t)row * 8192 + q];
    }

    // ---------------- producer: ws/coef for blocks 0..255 ----------------
    if (g < 256) {
        if (tid < 8) out[g * 8 + tid] = 0.0f;   // zero out slice pre-release

        const int j = g >> 4;
        const int chunk = g & 15;
        const int sub = tid >> 6;      // wave = a/m quarter
        const int lane = tid & 63;
        const int t = chunk * 64 + lane;
        const int tb = chunk * 64 + 64;
        const float2* A = (const float2*)ado;
        const float2* B = (const float2*)ado_wo;

        float w = 0.f, sx = 0.f, sy = 0.f;
        float wb = 0.f, sbx = 0.f, sby = 0.f;
        #pragma unroll
        for (int q = 0; q < 4; ++q) {
            int a = sub * 4 + q;
            float2 d = dd2(A, B, a * AA + j, t);
            float n = sqrtf(d.x * d.x + d.y * d.y);
            w += (n < EPSV) ? 0.f : 1.f / n;
            float2 e = dd2(A, B, j * AA + a, t);
            sx += e.x; sy += e.y;
            if (tb < TT) {
                float2 db = dd2(A, B, a * AA + j, tb);
                float nb = sqrtf(db.x * db.x + db.y * db.y);
                wb += (nb < EPSV) ? 0.f : 1.f / nb;
                float2 eb = dd2(A, B, j * AA + a, tb);
                sbx += eb.x; sby += eb.y;
            }
        }

        __shared__ float lw[4][64], lsx[4][64], lsy[4][64];
        __shared__ float lwb[4], lsbx[4], lsby[4];
        lw[sub][lane] = w; lsx[sub][lane] = sx; lsy[sub][lane] = sy;
        if (lane == 0) { lwb[sub] = wb; lsbx[sub] = sbx; lsby[sub] = sby; }
        __syncthreads();

        if (tid < 64) {
            float W  = lw[0][tid] + lw[1][tid] + lw[2][tid] + lw[3][tid];
            float SX = lsx[0][tid] + lsx[1][tid] + lsx[2][tid] + lsx[3][tid];
            float SY = lsy[0][tid] + lsy[1][tid] + lsy[2][tid] + lsy[3][tid];
            float wsx = W * SX, wsy = W * SY;
            float WB  = lwb[0] + lwb[1] + lwb[2] + lwb[3];
            float wbx = WB * (lsbx[0] + lsbx[1] + lsbx[2] + lsbx[3]);
            float wby = WB * (lsby[0] + lsby[1] + lsby[2] + lsby[3]);

            int tt = chunk * 64 + tid;
            *(float2*)(ws + tt * 32 + j * 2) = make_float2(wsx, wsy);

            float nx = __shfl_down(wsx, 1, 64);
            float ny = __shfl_down(wsy, 1, 64);
            if (tid == 63) { nx = wbx; ny = wby; }
            float cx = nx - 2.f * wsx;
            float cy = ny - 2.f * wsy;
            if (tt == TT - 1) { cx = 0.f; cy = 0.f; }
            *(float2*)(coef + tt * 32 + j * 2) = make_float2(cx, cy);
        }
        __syncthreads();
        __threadfence();   // publish ws/coef/out-zero device-wide
        if (tid == 0)
            __hip_atomic_fetch_add(flag, 1u, __ATOMIC_RELEASE,
                                   __HIP_MEMORY_SCOPE_AGENT);
    }

    // ---------------- acquire: wait for all 256 producers ----------------
    if (tid == 0) {
        while (__hip_atomic_load(flag, __ATOMIC_ACQUIRE,
                                 __HIP_MEMORY_SCOPE_AGENT) < 256u)
            __builtin_amdgcn_s_sleep(8);
    }
    __syncthreads();

    // ---------------- consumer: quarter-grad (R9-proven) ----------------
    float ax1 = 0.f, ay1 = 0.f, ax2 = 0.f, ay2 = 0.f;

    if (qi == 0 && tid < 8) {   // boundary slices u = k-2 (coeff ws[k-1])
        if (k1 >= 2) {
            f4 p  = pg4[(size_t)k1 * 8192 + (k1 - 2) * 8 + tid];
            f4 wv = ws4[(k1 - 1) * 8 + tid];
            ax1 += p.x * wv.x + p.z * wv.z;
            ay1 += p.y * wv.y + p.w * wv.w;
        }
        if (!dup) {
            f4 p  = pg4[(size_t)k2 * 8192 + (k2 - 2) * 8 + tid];
            f4 wv = ws4[(k2 - 1) * 8 + tid];
            ax2 += p.x * wv.x + p.z * wv.z;
            ay2 += p.y * wv.y + p.w * wv.w;
        }
    }

    #pragma unroll
    for (int i = 0; i < 4; ++i) {   // prefetched part
        int e = qi * 2048 + tid + 256 * i;
        bool s1 = (e < n1);
        if (pv[i]) {
            int q = s1 ? (base1 + e) : (base2 + (e - n1));
            f4 c = coef4[q];
            float px = pf[i].x * c.x + pf[i].z * c.z;
            float py = pf[i].y * c.y + pf[i].w * c.w;
            if (s1) { ax1 += px; ay1 += py; }
            else    { ax2 += px; ay2 += py; }
        }
    }
    #pragma unroll
    for (int i = 4; i < 8; ++i) {   // streamed part
        int e = qi * 2048 + tid + 256 * i;
        bool s1 = (e < n1);
        if (s1 || !dup) {
            int q = s1 ? (base1 + e) : (base2 + (e - n1));
            int row = s1 ? k1 : k2;
            f4 p = pg4[(size_t)row * 8192 + q];
            f4 c = coef4[q];
            float px = p.x * c.x + p.z * c.z;
            float py = p.y * c.y + p.w * c.w;
            if (s1) { ax1 += px; ay1 += py; }
            else    { ax2 += px; ay2 += py; }
        }
    }

    for (int off = 32; off > 0; off >>= 1) {
        ax1 += __shfl_down(ax1, off, 64);
        ay1 += __shfl_down(ay1, off, 64);
        ax2 += __shfl_down(ax2, off, 64);
        ay2 += __shfl_down(ay2, off, 64);
    }
    __shared__ float red[4][4];
    int wave = tid >> 6, lane = tid & 63;
    if (lane == 0) {
        red[wave][0] = ax1; red[wave][1] = ay1;
        red[wave][2] = ax2; red[wave][3] = ay2;
    }
    __syncthreads();
    if (tid < 2 && (tid == 0 || !dup)) {
        float rx = red[0][tid * 2] + red[1][tid * 2] + red[2][tid * 2] + red[3][tid * 2];
        float ry = red[0][tid * 2 + 1] + red[1][tid * 2 + 1] +
                   red[2][tid * 2 + 1] + red[3][tid * 2 + 1];
        int k = tid ? k2 : k1;
        atomicAdd(&out[2 * k + 0], rx);
        atomicAdd(&out[2 * k + 1], ry);
    }
}

extern "C" void kernel_launch(void* const* d_in, const int* in_sizes, int n_in,
                              void* d_out, int out_size, void* d_ws, size_t ws_size,
                              hipStream_t stream) {
    const float* ado    = (const float*)d_in[0];
    const float* ado_wo = (const float*)d_in[1];
    const float* pg     = (const float*)d_in[2];
    float* out  = (float*)d_out;
    float* ws   = (float*)d_ws;                          // 32768 floats
    float* coef = (float*)d_ws + TT * AA * 2;            // 32768 floats
    unsigned int* flag = (unsigned int*)((float*)d_ws + 2 * TT * AA * 2);

    hipMemsetAsync(flag, 0, sizeof(unsigned int), stream);
    fused_kernel<<<2048, 256, 0, stream>>>(ado, ado_wo, pg, ws, coef, flag, out);
}